// Round 3
// baseline (453.566 us; speedup 1.0000x reference)
//
#include <hip/hip_runtime.h>
#include <stdint.h>

#define NB 4096
#define NS 512
#define NA 64
#define NH1 1024
#define NH2 512

typedef __attribute__((ext_vector_type(8))) short bf16x8;
typedef __attribute__((ext_vector_type(4))) float f32x4;

__device__ __forceinline__ unsigned short f2bf(float f) {
    union { float f; unsigned u; } v; v.f = f;
    return (unsigned short)((v.u + 0x8000u) >> 16);   // round-half-up bf16
}
__device__ __forceinline__ float bf2f(unsigned short h) {
    union { float f; unsigned u; } v; v.u = ((unsigned)h) << 16;
    return v.f;
}
__device__ __forceinline__ float bflo(unsigned u) {
    union { unsigned u; float f; } v; v.u = u << 16; return v.f;
}
__device__ __forceinline__ float bfhi(unsigned u) {
    union { unsigned u; float f; } v; v.u = u & 0xFFFF0000u; return v.f;
}
// truncating pack of two f32 -> bf16x2 (bias cancels in u/||u||): 1 v_perm
__device__ __forceinline__ unsigned packtrunc(float lo, float hi) {
    union { float f; unsigned u; } a, b; a.f = lo; b.f = hi;
    return __builtin_amdgcn_perm(b.u, a.u, 0x07060302u);
}
__device__ __forceinline__ void split2(float x, unsigned short& h, unsigned short& l) {
    unsigned short hh = f2bf(x);
    h = hh;
    l = f2bf(x - bf2f(hh));
}
__device__ __forceinline__ void async_copy16(const void* g, void* l) {
    __builtin_amdgcn_global_load_lds((const __attribute__((address_space(1))) void*)g,
                                     (__attribute__((address_space(3))) void*)l, 16, 0, 0);
}

// ---------------- P0: nb[b] = sqrt(||s_b||^2 + 1) + 1e-8 ----------------
__global__ void knorm(const float* __restrict__ S, float* __restrict__ nb) {
    int b = blockIdx.x; int l = threadIdx.x; // one wave
    const float* row = S + b * NS;
    float s = 0.f;
    for (int k = l; k < NS; k += 64) { float v = row[k]; s = fmaf(v, v, s); }
    for (int off = 32; off; off >>= 1) s += __shfl_down(s, off, 64);
    if (l == 0) nb[b] = sqrtf(s + 1.0f) + 1e-8f;
}

// ---------------- P1: W2f (DMA-frag-packed per-kc tiles, swizzled) + caT2 ----------------
// W2f short idx = ((kc*32 + c)*64 + l)*8 + j :
//   n = c*16 + (l>>2);  g = (l&3) ^ ((n>>1)&3);  value = W2[n][kc*32 + g*8 + j]
// Per-kc tile = 32*64*8 shorts = 32 KB  (byte stride kc<<15 !)
// caT2[at][kc][a_loc][kk] = W1[(kc*32+kk)*576 + 512 + at*16 + a_loc]
__global__ void kprep(const float* __restrict__ W1, const float* __restrict__ W2,
                      unsigned short* __restrict__ W2f, unsigned short* __restrict__ caT2) {
    int i = blockIdx.x * 256 + threadIdx.x;
    if (i < 524288) {
        int j = i & 7; int l = (i >> 3) & 63; int c = (i >> 9) & 31; int kc = i >> 14;
        int n = c * 16 + (l >> 2);
        int g = (l & 3) ^ ((n >> 1) & 3);
        int k = kc * 32 + g * 8 + j;
        W2f[i] = f2bf(W2[(size_t)n * NH1 + k]);
    } else {
        int j2 = i - 524288;                 // 65536 entries
        int kk = j2 & 31; int a_loc = (j2 >> 5) & 15;
        int kc = (j2 >> 9) & 31; int att = j2 >> 14;
        int o = kc * 32 + kk;
        caT2[j2] = f2bf(W1[(size_t)o * 576 + 512 + att * 16 + a_loc]);
    }
}

// ---------------- P2: Gt'[kc][b][32k] bf16 = s@W1s^T + b1*nb  (split-bf16, 3 GEMMs) ----
__global__ __launch_bounds__(256) void kgemm1(
        const float* __restrict__ Sm, const float* __restrict__ W1,
        const float* __restrict__ b1, const float* __restrict__ nb,
        unsigned short* __restrict__ Gt) {
    const int m0 = (blockIdx.x >> 3) * 128;
    const int n0 = (blockIdx.x & 7) * 128;
    __shared__ unsigned short Ah[128][40], Al[128][40], Bh[128][40], Bl[128][40];
    int t = threadIdx.x;
    int lane = t & 63, wave = t >> 6;
    int wr = wave >> 1, wc = wave & 1;
    int qd = lane >> 4, cl = lane & 15;
    int r = t >> 1, seg = t & 1;
    f32x4 acc[4][4] = {};

    for (int k0 = 0; k0 < 512; k0 += 32) {
        {
            const float4* as4 = (const float4*)(Sm + (size_t)(m0 + r) * NS + k0 + seg * 16);
            const float4* bs4 = (const float4*)(W1 + (size_t)(n0 + r) * 576 + k0 + seg * 16);
            unsigned* ah = (unsigned*)&Ah[r][seg * 16];
            unsigned* al = (unsigned*)&Al[r][seg * 16];
            unsigned* bh = (unsigned*)&Bh[r][seg * 16];
            unsigned* bl = (unsigned*)&Bl[r][seg * 16];
#pragma unroll
            for (int v = 0; v < 4; v++) {
                float4 fa = as4[v];
                unsigned short h0,h1,h2,h3,l0,l1,l2,l3;
                split2(fa.x,h0,l0); split2(fa.y,h1,l1); split2(fa.z,h2,l2); split2(fa.w,h3,l3);
                ah[v*2]   = (unsigned)h0 | ((unsigned)h1 << 16);
                ah[v*2+1] = (unsigned)h2 | ((unsigned)h3 << 16);
                al[v*2]   = (unsigned)l0 | ((unsigned)l1 << 16);
                al[v*2+1] = (unsigned)l2 | ((unsigned)l3 << 16);
                float4 fb = bs4[v];
                split2(fb.x,h0,l0); split2(fb.y,h1,l1); split2(fb.z,h2,l2); split2(fb.w,h3,l3);
                bh[v*2]   = (unsigned)h0 | ((unsigned)h1 << 16);
                bh[v*2+1] = (unsigned)h2 | ((unsigned)h3 << 16);
                bl[v*2]   = (unsigned)l0 | ((unsigned)l1 << 16);
                bl[v*2+1] = (unsigned)l2 | ((unsigned)l3 << 16);
            }
        }
        __syncthreads();
        bf16x8 a_h[4], a_l[4], b_h[4], b_l[4];
#pragma unroll
        for (int mt = 0; mt < 4; mt++) {
            a_h[mt] = *(const bf16x8*)&Ah[wr*64 + mt*16 + cl][qd*8];
            a_l[mt] = *(const bf16x8*)&Al[wr*64 + mt*16 + cl][qd*8];
        }
#pragma unroll
        for (int nt = 0; nt < 4; nt++) {
            b_h[nt] = *(const bf16x8*)&Bh[wc*64 + nt*16 + cl][qd*8];
            b_l[nt] = *(const bf16x8*)&Bl[wc*64 + nt*16 + cl][qd*8];
        }
#pragma unroll
        for (int mt = 0; mt < 4; mt++)
#pragma unroll
            for (int nt = 0; nt < 4; nt++) {
                acc[mt][nt] = __builtin_amdgcn_mfma_f32_16x16x32_bf16(a_h[mt], b_h[nt], acc[mt][nt], 0, 0, 0);
                acc[mt][nt] = __builtin_amdgcn_mfma_f32_16x16x32_bf16(a_h[mt], b_l[nt], acc[mt][nt], 0, 0, 0);
                acc[mt][nt] = __builtin_amdgcn_mfma_f32_16x16x32_bf16(a_l[mt], b_h[nt], acc[mt][nt], 0, 0, 0);
            }
        __syncthreads();
    }
#pragma unroll
    for (int mt = 0; mt < 4; mt++)
#pragma unroll
        for (int i = 0; i < 4; i++) {
            int m = m0 + wr*64 + mt*16 + qd*4 + i;
            float nbv = nb[m];
#pragma unroll
            for (int nt = 0; nt < 4; nt++) {
                int n = n0 + wc*64 + nt*16 + cl;
                float val = fmaf(b1[n], nbv, acc[mt][nt][i]);
                Gt[((size_t)(n >> 5) * NB + m) * 32 + (n & 31)] = f2bf(val);
            }
        }
}

// ---------------- Main: 512 thr, 128 rows (16a x 8b) x 512 cols, K=1024, Kc=32 ----------
// grid 2048 = 512 bt x 4 at. 8 waves: wr = w>>2 (row half), wc = w&3 (col quarter).
// R8: A-path fully in registers. Key identity: for af row r = wr*64+mt*16+l15,
// Gt row = bt*8+(r&7) = bt*8+(l15&7) -- independent of mt/wr. So each lane loads
// 1x16B Gt + 4x16B caT2 (L1-hot), computes u = relu(g+c) and packs af[0..3]
// directly. No As LDS round-trip, no agen barrier: ONE barrier/iter (Bs dbuf
// flip), counted vmcnt(5) keeps the 5 g/c prefetch loads in flight across it.
// ||u||^2: lane accumulates its (row,k-octet) partials (same grouping/order as
// old kd-split -> numerically identical), reduced via shfl_xor(16,32) at end.
__global__ __launch_bounds__(512, 2) void kmain(
        const unsigned short* __restrict__ Gt,    // [32][4096][32]
        const unsigned short* __restrict__ caT2,  // [4][32][16][32]
        const unsigned short* __restrict__ W2f,   // per-kc frag-packed tiles (32 KB each)
        const float* __restrict__ nb,
        const float* __restrict__ b2, const float* __restrict__ Wq,
        const float* __restrict__ bq, float* __restrict__ out) {
    int bid = blockIdx.x;
    int at = bid & 3;
    int bt = bid >> 2;

    __shared__ __align__(16) unsigned short Bs[2][16384];    // 2 x 32 KB dbuf, swizzled
    __shared__ float invnh[128];
    __shared__ float qred[128][4];

    int t = threadIdx.x;
    int lane = t & 63, w = t >> 6;
    int wr = w >> 2, wc = w & 3;
    int l15 = lane & 15, l4 = lane >> 4;

    // direct A-frag global sources (L1-resident regions)
    const unsigned short* gGp = Gt + ((size_t)(bt * 8 + (l15 & 7))) * 32 + l4 * 8;
    const unsigned short* gCp = caT2 + (size_t)at * 16384 + (wr * 8 + (l15 >> 3)) * 32 + l4 * 8;

    f32x4 acc[4][8] = {};
    float sq0 = 0.f, sq1 = 0.f, sq2 = 0.f, sq3 = 0.f;
    bf16x8 g_v, c_v0, c_v1, c_v2, c_v3;

    const bool do_sq = (wc == 0);   // only wc==0 waves' norms are used

    auto fillB = [&](int kc, int s) {
        // per-kc tile stride = 32 KB (kc << 15)
        const char* gs = (const char*)W2f + ((size_t)kc << 15) + w * 1024 + (lane << 4);
        char* ld = (char*)Bs[s] + w * 1024 + (lane << 4);
        async_copy16(gs, ld);
        async_copy16(gs + 8192, ld + 8192);
        async_copy16(gs + 16384, ld + 16384);
        async_copy16(gs + 24576, ld + 24576);
    };

    // u-gen for one mt: af = packtrunc(relu(g+c)), optional sq accumulate
    auto afgen = [&](const bf16x8& cv, const float* gl, const float* gh, float& sqm) -> bf16x8 {
        const unsigned* cd = (const unsigned*)&cv;
        unsigned ow[4];
#pragma unroll
        for (int p = 0; p < 4; p++) {
            float u0 = fmaxf(gl[p] + bflo(cd[p]), 0.f);
            float u1 = fmaxf(gh[p] + bfhi(cd[p]), 0.f);
            if (do_sq) { sqm = fmaf(u0, u0, sqm); sqm = fmaf(u1, u1, sqm); }
            ow[p] = packtrunc(u0, u1);
        }
        return *(bf16x8*)ow;
    };

    // prologue: loads(0) + fill(0->slot0), drain, barrier
    g_v  = *(const bf16x8*)gGp;
    c_v0 = *(const bf16x8*)(gCp);
    c_v1 = *(const bf16x8*)(gCp + 64);
    c_v2 = *(const bf16x8*)(gCp + 128);
    c_v3 = *(const bf16x8*)(gCp + 192);
    fillB(0, 0);
    asm volatile("s_waitcnt vmcnt(0)" ::: "memory");
    __builtin_amdgcn_s_barrier();

    // hoisted B frag base (swizzle (l15>>1)&3 is nt-independent)
    const int boff = (wc * 128 + l15) * 32 + ((l4 ^ ((l15 >> 1) & 3)) << 3);

    for (int it = 0; it < 32; ++it) {
        int s = it & 1;

        // ---- B frags from LDS ----
        bf16x8 bfr[8];
        const unsigned short* bb2 = Bs[s] + boff;
#pragma unroll
        for (int nt = 0; nt < 8; nt++)
            bfr[nt] = *(const bf16x8*)(bb2 + nt * 512);

        // ---- A frags in-register from g/c (no LDS) ----
        bf16x8 af[4];
        {
            const unsigned* gd = (const unsigned*)&g_v;
            float gl[4], gh[4];
#pragma unroll
            for (int p = 0; p < 4; p++) { gl[p] = bflo(gd[p]); gh[p] = bfhi(gd[p]); }
            af[0] = afgen(c_v0, gl, gh, sq0);
            af[1] = afgen(c_v1, gl, gh, sq1);
            af[2] = afgen(c_v2, gl, gh, sq2);
            af[3] = afgen(c_v3, gl, gh, sq3);
        }

        // ---- prefetch next iter: B DMA (4) then g/c loads (5) ----
        if (it < 31) {
            fillB(it + 1, s ^ 1);
            gGp += (size_t)NB * 32;
            gCp += 512;
            g_v  = *(const bf16x8*)gGp;
            c_v0 = *(const bf16x8*)(gCp);
            c_v1 = *(const bf16x8*)(gCp + 64);
            c_v2 = *(const bf16x8*)(gCp + 128);
            c_v3 = *(const bf16x8*)(gCp + 192);
        }

        // ---- MFMA burst: 32 x 16x16x32 ----
        __builtin_amdgcn_s_setprio(1);
#pragma unroll
        for (int mt = 0; mt < 4; mt++)
#pragma unroll
            for (int nt = 0; nt < 8; nt++)
                acc[mt][nt] = __builtin_amdgcn_mfma_f32_16x16x32_bf16(af[mt], bfr[nt], acc[mt][nt], 0, 0, 0);
        __builtin_amdgcn_s_setprio(0);

        // ---- dbuf flip: own fills drained (5 g/c loads stay in flight) ----
        asm volatile("s_waitcnt vmcnt(5) lgkmcnt(0)" ::: "memory");
        __builtin_amdgcn_s_barrier();
    }

    // ---- ||u|| per row: reduce partials across the 4 l4-groups ----
    sq0 += __shfl_xor(sq0, 16, 64); sq0 += __shfl_xor(sq0, 32, 64);
    sq1 += __shfl_xor(sq1, 16, 64); sq1 += __shfl_xor(sq1, 32, 64);
    sq2 += __shfl_xor(sq2, 16, 64); sq2 += __shfl_xor(sq2, 32, 64);
    sq3 += __shfl_xor(sq3, 16, 64); sq3 += __shfl_xor(sq3, 32, 64);
    if (wc == 0 && l4 == 0) {
        float nbv = nb[bt * 8 + (l15 & 7)];
        invnh[wr * 64 +  0 + l15] = 1.0f / (sqrtf(sq0) + 1e-8f * nbv);
        invnh[wr * 64 + 16 + l15] = 1.0f / (sqrtf(sq1) + 1e-8f * nbv);
        invnh[wr * 64 + 32 + l15] = 1.0f / (sqrtf(sq2) + 1e-8f * nbv);
        invnh[wr * 64 + 48 + l15] = 1.0f / (sqrtf(sq3) + 1e-8f * nbv);
    }
    __syncthreads();

    // ---- epilogue: z = acc*invnh + b2; relu; q = sum(Wq*z) ----
    float wqv[8], b2v[8];
#pragma unroll
    for (int nt = 0; nt < 8; nt++) {
        int o = wc * 128 + nt * 16 + l15;
        wqv[nt] = Wq[o]; b2v[nt] = b2[o];
    }
#pragma unroll
    for (int mt = 0; mt < 4; mt++) {
#pragma unroll
        for (int i = 0; i < 4; i++) {
            int R = wr * 64 + mt * 16 + l4 * 4 + i;
            float inv = invnh[R];
            float qp = 0.f;
#pragma unroll
            for (int nt = 0; nt < 8; nt++) {
                float z = fmaf(acc[mt][nt][i], inv, b2v[nt]);
                z = fmaxf(z, 0.f);
                qp = fmaf(z, wqv[nt], qp);
            }
            qp += __shfl_xor(qp, 1, 64);
            qp += __shfl_xor(qp, 2, 64);
            qp += __shfl_xor(qp, 4, 64);
            qp += __shfl_xor(qp, 8, 64);
            if (l15 == 0) qred[R][wc] = qp;
        }
    }
    __syncthreads();
    if (t < 128) {
        float qv = qred[t][0] + qred[t][1] + qred[t][2] + qred[t][3] + bq[0];
        int aa = at * 16 + (t >> 3);
        int bo = bt * 8 + (t & 7);
        out[(size_t)bo * NA + aa] = qv;
    }
}

extern "C" void kernel_launch(void* const* d_in, const int* in_sizes, int n_in,
                              void* d_out, int out_size, void* d_ws, size_t ws_size,
                              hipStream_t stream) {
    const float* states = (const float*)d_in[0];
    const float* W1     = (const float*)d_in[1];
    const float* b1     = (const float*)d_in[2];
    const float* W2     = (const float*)d_in[3];
    const float* b2     = (const float*)d_in[4];
    const float* Wq     = (const float*)d_in[5];
    const float* bq     = (const float*)d_in[6];
    float* out = (float*)d_out;

    char* ws = (char*)d_ws;
    unsigned short* Gt   = (unsigned short*)ws;                              // 8 MB
    unsigned short* W2f  = (unsigned short*)(ws + (8u << 20));               // 1 MB
    unsigned short* caT2 = (unsigned short*)(ws + (9u << 20));               // 128 KB
    float*          nbp  = (float*)(ws + (9u << 20) + (128u << 10));         // 16 KB

    knorm<<<NB, 64, 0, stream>>>(states, nbp);
    kprep<<<2304, 256, 0, stream>>>(W1, W2, W2f, caT2);
    kgemm1<<<256, 256, 0, stream>>>(states, W1, b1, nbp, Gt);
    kmain<<<2048, 512, 0, stream>>>(Gt, caT2, W2f, nbp, b2, Wq, bq, out);
}

// Round 4
// 404.070 us; speedup vs baseline: 1.1225x; 1.1225x over previous
//
#include <hip/hip_runtime.h>
#include <stdint.h>

#define NB 4096
#define NS 512
#define NA 64
#define NH1 1024
#define NH2 512

typedef __attribute__((ext_vector_type(8))) short bf16x8;
typedef __attribute__((ext_vector_type(4))) float f32x4;

__device__ __forceinline__ unsigned short f2bf(float f) {
    union { float f; unsigned u; } v; v.f = f;
    return (unsigned short)((v.u + 0x8000u) >> 16);   // round-half-up bf16
}
__device__ __forceinline__ float bf2f(unsigned short h) {
    union { float f; unsigned u; } v; v.u = ((unsigned)h) << 16;
    return v.f;
}
__device__ __forceinline__ float bflo(unsigned u) {
    union { unsigned u; float f; } v; v.u = u << 16; return v.f;
}
__device__ __forceinline__ float bfhi(unsigned u) {
    union { unsigned u; float f; } v; v.u = u & 0xFFFF0000u; return v.f;
}
// truncating pack of two f32 -> bf16x2 (bias cancels in u/||u||): 1 v_perm
__device__ __forceinline__ unsigned packtrunc(float lo, float hi) {
    union { float f; unsigned u; } a, b; a.f = lo; b.f = hi;
    return __builtin_amdgcn_perm(b.u, a.u, 0x07060302u);
}
__device__ __forceinline__ void split2(float x, unsigned short& h, unsigned short& l) {
    unsigned short hh = f2bf(x);
    h = hh;
    l = f2bf(x - bf2f(hh));
}
__device__ __forceinline__ void async_copy16(const void* g, void* l) {
    __builtin_amdgcn_global_load_lds((const __attribute__((address_space(1))) void*)g,
                                     (__attribute__((address_space(3))) void*)l, 16, 0, 0);
}

// ---------------- P0: nb[b] = sqrt(||s_b||^2 + 1) + 1e-8 ----------------
__global__ void knorm(const float* __restrict__ S, float* __restrict__ nb) {
    int b = blockIdx.x; int l = threadIdx.x; // one wave
    const float* row = S + b * NS;
    float s = 0.f;
    for (int k = l; k < NS; k += 64) { float v = row[k]; s = fmaf(v, v, s); }
    for (int off = 32; off; off >>= 1) s += __shfl_down(s, off, 64);
    if (l == 0) nb[b] = sqrtf(s + 1.0f) + 1e-8f;
}

// ---------------- P1: W2f (DMA-frag-packed per-kc tiles, swizzled) + caT2 ----------------
// W2f short idx = ((kc*32 + c)*64 + l)*8 + j :
//   n = c*16 + (l>>2);  g = (l&3) ^ ((n>>1)&3);  value = W2[n][kc*32 + g*8 + j]
// Per-kc tile = 32*64*8 shorts = 32 KB  (byte stride kc<<15 !)
// caT2[at][kc][a_loc][kk] = W1[(kc*32+kk)*576 + 512 + at*16 + a_loc]
__global__ void kprep(const float* __restrict__ W1, const float* __restrict__ W2,
                      unsigned short* __restrict__ W2f, unsigned short* __restrict__ caT2) {
    int i = blockIdx.x * 256 + threadIdx.x;
    if (i < 524288) {
        int j = i & 7; int l = (i >> 3) & 63; int c = (i >> 9) & 31; int kc = i >> 14;
        int n = c * 16 + (l >> 2);
        int g = (l & 3) ^ ((n >> 1) & 3);
        int k = kc * 32 + g * 8 + j;
        W2f[i] = f2bf(W2[(size_t)n * NH1 + k]);
    } else {
        int j2 = i - 524288;                 // 65536 entries
        int kk = j2 & 31; int a_loc = (j2 >> 5) & 15;
        int kc = (j2 >> 9) & 31; int att = j2 >> 14;
        int o = kc * 32 + kk;
        caT2[j2] = f2bf(W1[(size_t)o * 576 + 512 + att * 16 + a_loc]);
    }
}

// ---------------- P2: Gt'[kc][b][32k] bf16 = s@W1s^T + b1*nb  (split-bf16, 3 GEMMs) ----
__global__ __launch_bounds__(256) void kgemm1(
        const float* __restrict__ Sm, const float* __restrict__ W1,
        const float* __restrict__ b1, const float* __restrict__ nb,
        unsigned short* __restrict__ Gt) {
    const int m0 = (blockIdx.x >> 3) * 128;
    const int n0 = (blockIdx.x & 7) * 128;
    __shared__ unsigned short Ah[128][40], Al[128][40], Bh[128][40], Bl[128][40];
    int t = threadIdx.x;
    int lane = t & 63, wave = t >> 6;
    int wr = wave >> 1, wc = wave & 1;
    int qd = lane >> 4, cl = lane & 15;
    int r = t >> 1, seg = t & 1;
    f32x4 acc[4][4] = {};

    for (int k0 = 0; k0 < 512; k0 += 32) {
        {
            const float4* as4 = (const float4*)(Sm + (size_t)(m0 + r) * NS + k0 + seg * 16);
            const float4* bs4 = (const float4*)(W1 + (size_t)(n0 + r) * 576 + k0 + seg * 16);
            unsigned* ah = (unsigned*)&Ah[r][seg * 16];
            unsigned* al = (unsigned*)&Al[r][seg * 16];
            unsigned* bh = (unsigned*)&Bh[r][seg * 16];
            unsigned* bl = (unsigned*)&Bl[r][seg * 16];
#pragma unroll
            for (int v = 0; v < 4; v++) {
                float4 fa = as4[v];
                unsigned short h0,h1,h2,h3,l0,l1,l2,l3;
                split2(fa.x,h0,l0); split2(fa.y,h1,l1); split2(fa.z,h2,l2); split2(fa.w,h3,l3);
                ah[v*2]   = (unsigned)h0 | ((unsigned)h1 << 16);
                ah[v*2+1] = (unsigned)h2 | ((unsigned)h3 << 16);
                al[v*2]   = (unsigned)l0 | ((unsigned)l1 << 16);
                al[v*2+1] = (unsigned)l2 | ((unsigned)l3 << 16);
                float4 fb = bs4[v];
                split2(fb.x,h0,l0); split2(fb.y,h1,l1); split2(fb.z,h2,l2); split2(fb.w,h3,l3);
                bh[v*2]   = (unsigned)h0 | ((unsigned)h1 << 16);
                bh[v*2+1] = (unsigned)h2 | ((unsigned)h3 << 16);
                bl[v*2]   = (unsigned)l0 | ((unsigned)l1 << 16);
                bl[v*2+1] = (unsigned)l2 | ((unsigned)l3 << 16);
            }
        }
        __syncthreads();
        bf16x8 a_h[4], a_l[4], b_h[4], b_l[4];
#pragma unroll
        for (int mt = 0; mt < 4; mt++) {
            a_h[mt] = *(const bf16x8*)&Ah[wr*64 + mt*16 + cl][qd*8];
            a_l[mt] = *(const bf16x8*)&Al[wr*64 + mt*16 + cl][qd*8];
        }
#pragma unroll
        for (int nt = 0; nt < 4; nt++) {
            b_h[nt] = *(const bf16x8*)&Bh[wc*64 + nt*16 + cl][qd*8];
            b_l[nt] = *(const bf16x8*)&Bl[wc*64 + nt*16 + cl][qd*8];
        }
#pragma unroll
        for (int mt = 0; mt < 4; mt++)
#pragma unroll
            for (int nt = 0; nt < 4; nt++) {
                acc[mt][nt] = __builtin_amdgcn_mfma_f32_16x16x32_bf16(a_h[mt], b_h[nt], acc[mt][nt], 0, 0, 0);
                acc[mt][nt] = __builtin_amdgcn_mfma_f32_16x16x32_bf16(a_h[mt], b_l[nt], acc[mt][nt], 0, 0, 0);
                acc[mt][nt] = __builtin_amdgcn_mfma_f32_16x16x32_bf16(a_l[mt], b_h[nt], acc[mt][nt], 0, 0, 0);
            }
        __syncthreads();
    }
#pragma unroll
    for (int mt = 0; mt < 4; mt++)
#pragma unroll
        for (int i = 0; i < 4; i++) {
            int m = m0 + wr*64 + mt*16 + qd*4 + i;
            float nbv = nb[m];
#pragma unroll
            for (int nt = 0; nt < 4; nt++) {
                int n = n0 + wc*64 + nt*16 + cl;
                float val = fmaf(b1[n], nbv, acc[mt][nt][i]);
                Gt[((size_t)(n >> 5) * NB + m) * 32 + (n & 31)] = f2bf(val);
            }
        }
}

// ---------------- Main: 512 thr, 128 rows (16a x 8b) x 512 cols, K=1024, Kc=32 ----------
// grid 2048 = 512 bt x 4 at. 8 waves: wr = w>>2 (row half), wc = w&3 (col quarter).
// R9: rolling-read MFMA stream. R5/R7 executed {12 ds_reads} then {32 MFMA} as
// disjoint phases (R7's lgkmcnt(0)+sched_barrier pins even enforced it) ->
// ~1200 cyc LDS burst + ~1242 cyc MFMA burst = ~3000 cyc/iter. Here: read
// af[0..3]+bfr[0] (5 reads), then nt-outer loop {read bfr[nt+1]; 4 MFMA on
// bfr[nt]} pinned via sched_group_barrier{DS_READ x1, MFMA x4} so the
// scheduler cannot re-clump reads. MFMA starts after 5 reads; remaining 7
// reads + fill DMA + agen hide under the MFMA stream. One barrier/iter;
// publish uses counted vmcnt(2) (2 g/c prefetch loads stay in flight).
__global__ __launch_bounds__(512, 2) void kmain(
        const unsigned short* __restrict__ Gt,    // [32][4096][32]
        const unsigned short* __restrict__ caT2,  // [4][32][16][32]
        const unsigned short* __restrict__ W2f,   // per-kc frag-packed tiles (32 KB each)
        const float* __restrict__ nb,
        const float* __restrict__ b2, const float* __restrict__ Wq,
        const float* __restrict__ bq, float* __restrict__ out) {
    int bid = blockIdx.x;
    int at = bid & 3;
    int bt = bid >> 2;

    __shared__ __align__(16) unsigned short As[2][128][40];  // 2 x 10 KB dbuf, pad +8
    __shared__ __align__(16) unsigned short Bs[2][16384];    // 2 x 32 KB dbuf, swizzled
    __shared__ float invnh[128];
    __shared__ float qred[128][4];

    int t = threadIdx.x;
    int lane = t & 63, w = t >> 6;
    int wr = w >> 2, wc = w & 3;
    int l15 = lane & 15, l4 = lane >> 4;

    // A-gen role: thread owns row (t>>2), k-octet (t&3); 8 elements/iter
    int row = t >> 2, kd = t & 3;
    int ab = row >> 3, bb = row & 7;
    const unsigned short* gG = Gt + ((size_t)(bt * 8 + bb)) * 32 + kd * 8;
    const unsigned short* gC = caT2 + (size_t)at * 16384 + ab * 32 + kd * 8;

    float sq = 0.f;
    f32x4 acc[4][8] = {};
    bf16x8 g_v, c_v;

    auto fillB = [&](int kc, int s) {
        // per-kc tile stride = 32 KB (kc << 15)
        const char* gs = (const char*)W2f + ((size_t)kc << 15) + w * 1024 + (lane << 4);
        char* ld = (char*)Bs[s] + w * 1024 + (lane << 4);
        async_copy16(gs, ld);
        async_copy16(gs + 8192, ld + 8192);
        async_copy16(gs + 16384, ld + 16384);
        async_copy16(gs + 24576, ld + 24576);
    };
    auto agen = [&](int s) {
        const unsigned* gd = (const unsigned*)&g_v;
        const unsigned* cd = (const unsigned*)&c_v;
        unsigned ow[4];
#pragma unroll
        for (int p = 0; p < 4; p++) {
            float u0 = fmaxf(bflo(gd[p]) + bflo(cd[p]), 0.f);
            float u1 = fmaxf(bfhi(gd[p]) + bfhi(cd[p]), 0.f);
            sq = fmaf(u0, u0, sq);
            sq = fmaf(u1, u1, sq);
            ow[p] = packtrunc(u0, u1);
        }
        *(bf16x8*)&As[s][row][kd * 8] = *(bf16x8*)ow;
    };

    // prologue: gen(0), fill B(0), prefetch g/c(1); counted publish
    g_v = *(const bf16x8*)gG;
    c_v = *(const bf16x8*)gC;
    agen(0);
    fillB(0, 0);
    gG += (size_t)NB * 32;
    gC += 512;
    g_v = *(const bf16x8*)gG;          // g/c(1): 2 newest outstanding
    c_v = *(const bf16x8*)gC;
    asm volatile("s_waitcnt vmcnt(2)" ::: "memory");   // fill(0) landed
    asm volatile("s_waitcnt lgkmcnt(0)" ::: "memory"); // agen(0) write done
    __builtin_amdgcn_s_barrier();

    // hoisted B frag base (swizzle (l15>>1)&3 is nt-independent)
    const int boff = (wc * 128 + l15) * 32 + ((l4 ^ ((l15 >> 1) & 3)) << 3);

    for (int it = 0; it < 32; ++it) {
        int s = it & 1;

        // ---- startup reads: af x4 + bfr[0] (5 ds_reads on MFMA critical path) ----
        bf16x8 af[4], bfr[8];
#pragma unroll
        for (int mt = 0; mt < 4; mt++)
            af[mt] = *(const bf16x8*)&As[s][wr * 64 + mt * 16 + l15][l4 * 8];
        const unsigned short* bb2 = Bs[s] + boff;
        bfr[0] = *(const bf16x8*)(bb2);

        // ---- issue next-iter work: DMA fill, A-gen (VALU + ds_write), g/c loads ----
        if (it < 31) {
            fillB(it + 1, s ^ 1);       // 4 DMA into other B slot; in flight until publish
            agen(s ^ 1);                // u(it+1) -> other A slot (reads g_v/c_v)
            if (it < 30) {
                gG += (size_t)NB * 32;
                gC += 512;
                g_v = *(const bf16x8*)gG;   // for agen(it+2)
                c_v = *(const bf16x8*)gC;
            }
        }

        // ---- rolling MFMA stream: {read bfr[nt+1]; 4 MFMA on bfr[nt]} x8 ----
        __builtin_amdgcn_s_setprio(1);
#pragma unroll
        for (int nt = 0; nt < 8; nt++) {
            if (nt < 7)
                bfr[nt + 1] = *(const bf16x8*)(bb2 + (nt + 1) * 512);
#pragma unroll
            for (int mt = 0; mt < 4; mt++)
                acc[mt][nt] = __builtin_amdgcn_mfma_f32_16x16x32_bf16(af[mt], bfr[nt], acc[mt][nt], 0, 0, 0);
            if (nt < 7)
                __builtin_amdgcn_sched_group_barrier(0x100, 1, 0);  // 1 DS_READ
            __builtin_amdgcn_sched_group_barrier(0x008, 4, 0);      // 4 MFMA
        }
        __builtin_amdgcn_s_setprio(0);

        // ---- publish: fills drained (counted), agen write visible; flip ----
        if (it < 30) {
            asm volatile("s_waitcnt vmcnt(2)" ::: "memory");   // 4 fills done; 2 g/c in flight
        } else if (it == 30) {
            asm volatile("s_waitcnt vmcnt(0)" ::: "memory");   // no g/c outstanding; drain last fill
        }
        asm volatile("s_waitcnt lgkmcnt(0)" ::: "memory");
        __builtin_amdgcn_sched_barrier(0);
        __builtin_amdgcn_s_barrier();
    }

    // ---- ||u|| per row: reduce over 4 kd threads (consecutive lanes) ----
    sq += __shfl_xor(sq, 1, 64);
    sq += __shfl_xor(sq, 2, 64);
    if (kd == 0) invnh[row] = 1.0f / (sqrtf(sq) + 1e-8f * nb[bt * 8 + bb]);
    __syncthreads();

    // ---- epilogue: z = acc*invnh + b2; relu; q = sum(Wq*z) ----
    float wqv[8], b2v[8];
#pragma unroll
    for (int nt = 0; nt < 8; nt++) {
        int o = wc * 128 + nt * 16 + l15;
        wqv[nt] = Wq[o]; b2v[nt] = b2[o];
    }
#pragma unroll
    for (int mt = 0; mt < 4; mt++) {
#pragma unroll
        for (int i = 0; i < 4; i++) {
            int R = wr * 64 + mt * 16 + l4 * 4 + i;
            float inv = invnh[R];
            float qp = 0.f;
#pragma unroll
            for (int nt = 0; nt < 8; nt++) {
                float z = fmaf(acc[mt][nt][i], inv, b2v[nt]);
                z = fmaxf(z, 0.f);
                qp = fmaf(z, wqv[nt], qp);
            }
            qp += __shfl_xor(qp, 1, 64);
            qp += __shfl_xor(qp, 2, 64);
            qp += __shfl_xor(qp, 4, 64);
            qp += __shfl_xor(qp, 8, 64);
            if (l15 == 0) qred[R][wc] = qp;
        }
    }
    __syncthreads();
    if (t < 128) {
        float qv = qred[t][0] + qred[t][1] + qred[t][2] + qred[t][3] + bq[0];
        int aa = at * 16 + (t >> 3);
        int bo = bt * 8 + (t & 7);
        out[(size_t)bo * NA + aa] = qv;
    }
}

extern "C" void kernel_launch(void* const* d_in, const int* in_sizes, int n_in,
                              void* d_out, int out_size, void* d_ws, size_t ws_size,
                              hipStream_t stream) {
    const float* states = (const float*)d_in[0];
    const float* W1     = (const float*)d_in[1];
    const float* b1     = (const float*)d_in[2];
    const float* W2     = (const float*)d_in[3];
    const float* b2     = (const float*)d_in[4];
    const float* Wq     = (const float*)d_in[5];
    const float* bq     = (const float*)d_in[6];
    float* out = (float*)d_out;

    char* ws = (char*)d_ws;
    unsigned short* Gt   = (unsigned short*)ws;                              // 8 MB
    unsigned short* W2f  = (unsigned short*)(ws + (8u << 20));               // 1 MB
    unsigned short* caT2 = (unsigned short*)(ws + (9u << 20));               // 128 KB
    float*          nbp  = (float*)(ws + (9u << 20) + (128u << 10));         // 16 KB

    knorm<<<NB, 64, 0, stream>>>(states, nbp);
    kprep<<<2304, 256, 0, stream>>>(W1, W2, W2f, caT2);
    kgemm1<<<256, 256, 0, stream>>>(states, W1, b1, nbp, Gt);
    kmain<<<2048, 512, 0, stream>>>(Gt, caT2, W2f, nbp, b2, Wq, bq, out);
}

// Round 5
// 361.458 us; speedup vs baseline: 1.2548x; 1.1179x over previous
//
#include <hip/hip_runtime.h>
#include <stdint.h>

#define NB 4096
#define NS 512
#define NA 64
#define NH1 1024
#define NH2 512

typedef __attribute__((ext_vector_type(8))) short bf16x8;
typedef __attribute__((ext_vector_type(4))) float f32x4;

__device__ __forceinline__ unsigned short f2bf(float f) {
    union { float f; unsigned u; } v; v.f = f;
    return (unsigned short)((v.u + 0x8000u) >> 16);   // round-half-up bf16
}
__device__ __forceinline__ float bf2f(unsigned short h) {
    union { float f; unsigned u; } v; v.u = ((unsigned)h) << 16;
    return v.f;
}
__device__ __forceinline__ float bflo(unsigned u) {
    union { unsigned u; float f; } v; v.u = u << 16; return v.f;
}
__device__ __forceinline__ float bfhi(unsigned u) {
    union { unsigned u; float f; } v; v.u = u & 0xFFFF0000u; return v.f;
}
// truncating pack of two f32 -> bf16x2 (bias cancels in u/||u||): 1 v_perm
__device__ __forceinline__ unsigned packtrunc(float lo, float hi) {
    union { float f; unsigned u; } a, b; a.f = lo; b.f = hi;
    return __builtin_amdgcn_perm(b.u, a.u, 0x07060302u);
}
__device__ __forceinline__ void split2(float x, unsigned short& h, unsigned short& l) {
    unsigned short hh = f2bf(x);
    h = hh;
    l = f2bf(x - bf2f(hh));
}

// ---------------- P0: nb[b] = sqrt(||s_b||^2 + 1) + 1e-8 ----------------
__global__ void knorm(const float* __restrict__ S, float* __restrict__ nb) {
    int b = blockIdx.x; int l = threadIdx.x; // one wave
    const float* row = S + b * NS;
    float s = 0.f;
    for (int k = l; k < NS; k += 64) { float v = row[k]; s = fmaf(v, v, s); }
    for (int off = 32; off; off >>= 1) s += __shfl_down(s, off, 64);
    if (l == 0) nb[b] = sqrtf(s + 1.0f) + 1e-8f;
}

// ---------------- P1: W2f (frag-packed per-kc tiles, swizzled) + caT2 ----------------
// W2f short idx = ((kc*32 + c)*64 + l)*8 + j :
//   n = c*16 + (l>>2);  g = (l&3) ^ ((n>>1)&3);  value = W2[n][kc*32 + g*8 + j]
// Per-kc tile = 32*64*8 shorts = 32 KB
// caT2[at][kc][a_loc][kk] = W1[(kc*32+kk)*576 + 512 + at*16 + a_loc]
__global__ void kprep(const float* __restrict__ W1, const float* __restrict__ W2,
                      unsigned short* __restrict__ W2f, unsigned short* __restrict__ caT2) {
    int i = blockIdx.x * 256 + threadIdx.x;
    if (i < 524288) {
        int j = i & 7; int l = (i >> 3) & 63; int c = (i >> 9) & 31; int kc = i >> 14;
        int n = c * 16 + (l >> 2);
        int g = (l & 3) ^ ((n >> 1) & 3);
        int k = kc * 32 + g * 8 + j;
        W2f[i] = f2bf(W2[(size_t)n * NH1 + k]);
    } else {
        int j2 = i - 524288;                 // 65536 entries
        int kk = j2 & 31; int a_loc = (j2 >> 5) & 15;
        int kc = (j2 >> 9) & 31; int att = j2 >> 14;
        int o = kc * 32 + kk;
        caT2[j2] = f2bf(W1[(size_t)o * 576 + 512 + att * 16 + a_loc]);
    }
}

// ---------------- P2: Gt'[kc][b][32k] bf16 = s@W1s^T + b1*nb  (split-bf16, 3 GEMMs) ----
__global__ __launch_bounds__(256) void kgemm1(
        const float* __restrict__ Sm, const float* __restrict__ W1,
        const float* __restrict__ b1, const float* __restrict__ nb,
        unsigned short* __restrict__ Gt) {
    const int m0 = (blockIdx.x >> 3) * 128;
    const int n0 = (blockIdx.x & 7) * 128;
    __shared__ unsigned short Ah[128][40], Al[128][40], Bh[128][40], Bl[128][40];
    int t = threadIdx.x;
    int lane = t & 63, wave = t >> 6;
    int wr = wave >> 1, wc = wave & 1;
    int qd = lane >> 4, cl = lane & 15;
    int r = t >> 1, seg = t & 1;
    f32x4 acc[4][4] = {};

    for (int k0 = 0; k0 < 512; k0 += 32) {
        {
            const float4* as4 = (const float4*)(Sm + (size_t)(m0 + r) * NS + k0 + seg * 16);
            const float4* bs4 = (const float4*)(W1 + (size_t)(n0 + r) * 576 + k0 + seg * 16);
            unsigned* ah = (unsigned*)&Ah[r][seg * 16];
            unsigned* al = (unsigned*)&Al[r][seg * 16];
            unsigned* bh = (unsigned*)&Bh[r][seg * 16];
            unsigned* bl = (unsigned*)&Bl[r][seg * 16];
#pragma unroll
            for (int v = 0; v < 4; v++) {
                float4 fa = as4[v];
                unsigned short h0,h1,h2,h3,l0,l1,l2,l3;
                split2(fa.x,h0,l0); split2(fa.y,h1,l1); split2(fa.z,h2,l2); split2(fa.w,h3,l3);
                ah[v*2]   = (unsigned)h0 | ((unsigned)h1 << 16);
                ah[v*2+1] = (unsigned)h2 | ((unsigned)h3 << 16);
                al[v*2]   = (unsigned)l0 | ((unsigned)l1 << 16);
                al[v*2+1] = (unsigned)l2 | ((unsigned)l3 << 16);
                float4 fb = bs4[v];
                split2(fb.x,h0,l0); split2(fb.y,h1,l1); split2(fb.z,h2,l2); split2(fb.w,h3,l3);
                bh[v*2]   = (unsigned)h0 | ((unsigned)h1 << 16);
                bh[v*2+1] = (unsigned)h2 | ((unsigned)h3 << 16);
                bl[v*2]   = (unsigned)l0 | ((unsigned)l1 << 16);
                bl[v*2+1] = (unsigned)l2 | ((unsigned)l3 << 16);
            }
        }
        __syncthreads();
        bf16x8 a_h[4], a_l[4], b_h[4], b_l[4];
#pragma unroll
        for (int mt = 0; mt < 4; mt++) {
            a_h[mt] = *(const bf16x8*)&Ah[wr*64 + mt*16 + cl][qd*8];
            a_l[mt] = *(const bf16x8*)&Al[wr*64 + mt*16 + cl][qd*8];
        }
#pragma unroll
        for (int nt = 0; nt < 4; nt++) {
            b_h[nt] = *(const bf16x8*)&Bh[wc*64 + nt*16 + cl][qd*8];
            b_l[nt] = *(const bf16x8*)&Bl[wc*64 + nt*16 + cl][qd*8];
        }
#pragma unroll
        for (int mt = 0; mt < 4; mt++)
#pragma unroll
            for (int nt = 0; nt < 4; nt++) {
                acc[mt][nt] = __builtin_amdgcn_mfma_f32_16x16x32_bf16(a_h[mt], b_h[nt], acc[mt][nt], 0, 0, 0);
                acc[mt][nt] = __builtin_amdgcn_mfma_f32_16x16x32_bf16(a_h[mt], b_l[nt], acc[mt][nt], 0, 0, 0);
                acc[mt][nt] = __builtin_amdgcn_mfma_f32_16x16x32_bf16(a_l[mt], b_h[nt], acc[mt][nt], 0, 0, 0);
            }
        __syncthreads();
    }
#pragma unroll
    for (int mt = 0; mt < 4; mt++)
#pragma unroll
        for (int i = 0; i < 4; i++) {
            int m = m0 + wr*64 + mt*16 + qd*4 + i;
            float nbv = nb[m];
#pragma unroll
            for (int nt = 0; nt < 4; nt++) {
                int n = n0 + wc*64 + nt*16 + cl;
                float val = fmaf(b1[n], nbv, acc[mt][nt][i]);
                Gt[((size_t)(n >> 5) * NB + m) * 32 + (n & 31)] = f2bf(val);
            }
        }
}

// ---------------- Main: 512 thr, 128 rows (16a x 8b) x 512 cols, K=1024, Kc=32 ----------
// grid 2048 = 512 bt x 4 at. 8 waves: wr = w>>2 (row half), wc = w&3 (col quarter).
// R10: B never touches LDS. Rationale: per-iter LDS traffic was 136 KB
// (B reads 64K + B DMA-writes 32K + A reads 32K + A writes 8K) ~= 1210 cyc --
// equal to the 1242-cyc MFMA floor; the two pipes serialized (R7/R9 schedule
// variants all ~3100 cyc/iter). W2f is 1 MB, L2-resident, re-read 32x/block:
// read B frags DIRECTLY from global. Frag-packed layout => global addr =
// W2f + kc*16384 + boff + nt*512 (same boff as the old LDS read; each
// instruction covers a contiguous lane-permuted 1 KB = fully coalesced).
// bfr loads are software-pipelined one iter ahead IN THE SAME REGISTERS
// (issued after last MFMA use -> no extra liveness; ~600+ cyc to hide L2).
// LDS/iter drops to 40 KB (As path only); one lgkmcnt+barrier per iter.
__global__ __launch_bounds__(512, 2) void kmain(
        const unsigned short* __restrict__ Gt,    // [32][4096][32]
        const unsigned short* __restrict__ caT2,  // [4][32][16][32]
        const unsigned short* __restrict__ W2f,   // per-kc frag-packed tiles (32 KB each)
        const float* __restrict__ nb,
        const float* __restrict__ b2, const float* __restrict__ Wq,
        const float* __restrict__ bq, float* __restrict__ out) {
    int bid = blockIdx.x;
    int at = bid & 3;
    int bt = bid >> 2;

    __shared__ __align__(16) unsigned short As[2][128][40];  // 2 x 10 KB dbuf, pad +8
    __shared__ float invnh[128];
    __shared__ float qred[128][4];

    int t = threadIdx.x;
    int lane = t & 63, w = t >> 6;
    int wr = w >> 2, wc = w & 3;
    int l15 = lane & 15, l4 = lane >> 4;

    // A-gen role: thread owns row (t>>2), k-octet (t&3); 8 elements/iter
    int row = t >> 2, kd = t & 3;
    int ab = row >> 3, bb = row & 7;
    const unsigned short* gG = Gt + ((size_t)(bt * 8 + bb)) * 32 + kd * 8;
    const unsigned short* gC = caT2 + (size_t)at * 16384 + ab * 32 + kd * 8;

    float sq = 0.f;
    f32x4 acc[4][8] = {};
    bf16x8 g_v, c_v;

    auto agen = [&](int s) {
        const unsigned* gd = (const unsigned*)&g_v;
        const unsigned* cd = (const unsigned*)&c_v;
        unsigned ow[4];
#pragma unroll
        for (int p = 0; p < 4; p++) {
            float u0 = fmaxf(bflo(gd[p]) + bflo(cd[p]), 0.f);
            float u1 = fmaxf(bfhi(gd[p]) + bfhi(cd[p]), 0.f);
            sq = fmaf(u0, u0, sq);
            sq = fmaf(u1, u1, sq);
            ow[p] = packtrunc(u0, u1);
        }
        *(bf16x8*)&As[s][row][kd * 8] = *(bf16x8*)ow;
    };

    // B frag source: de-swizzled per-lane global address, iter-invariant offset
    const int boff = (wc * 128 + l15) * 32 + ((l4 ^ ((l15 >> 1) & 3)) << 3);
    const unsigned short* gB = W2f + boff;

    bf16x8 bfr[8];

    // prologue: gen(0), bfr(0) loads, prefetch g/c(1)
    g_v = *(const bf16x8*)gG;
    c_v = *(const bf16x8*)gC;
    agen(0);
#pragma unroll
    for (int nt = 0; nt < 8; nt++)
        bfr[nt] = *(const bf16x8*)(gB + nt * 512);
    gB += 16384;
    gG += (size_t)NB * 32;
    gC += 512;
    g_v = *(const bf16x8*)gG;
    c_v = *(const bf16x8*)gC;
    asm volatile("s_waitcnt lgkmcnt(0)" ::: "memory");   // agen(0) write visible
    __builtin_amdgcn_s_barrier();
    __builtin_amdgcn_sched_barrier(0);

    for (int it = 0; it < 32; ++it) {
        int s = it & 1;

        // ---- A frags from LDS (only LDS consumer left) ----
        bf16x8 af[4];
#pragma unroll
        for (int mt = 0; mt < 4; mt++)
            af[mt] = *(const bf16x8*)&As[s][wr * 64 + mt * 16 + l15][l4 * 8];

        // ---- produce next A tile + prefetch g/c(it+2) ----
        if (it < 31) agen(s ^ 1);
        if (it < 30) {
            gG += (size_t)NB * 32;
            gC += 512;
            g_v = *(const bf16x8*)gG;
            c_v = *(const bf16x8*)gC;
        }

        // ---- MFMA stream: 32 x 16x16x32 on current bfr (loaded last iter) ----
        __builtin_amdgcn_s_setprio(1);
#pragma unroll
        for (int nt = 0; nt < 8; nt++)
#pragma unroll
            for (int mt = 0; mt < 4; mt++)
                acc[mt][nt] = __builtin_amdgcn_mfma_f32_16x16x32_bf16(af[mt], bfr[nt], acc[mt][nt], 0, 0, 0);
        __builtin_amdgcn_s_setprio(0);

        // ---- reload bfr for it+1 (same regs: old values dead after MFMAs) ----
        if (it < 31) {
#pragma unroll
            for (int nt = 0; nt < 8; nt++)
                bfr[nt] = *(const bf16x8*)(gB + nt * 512);
            gB += 16384;
            // ---- As dbuf flip ----
            asm volatile("s_waitcnt lgkmcnt(0)" ::: "memory");  // agen write + af reads done
            __builtin_amdgcn_s_barrier();
            __builtin_amdgcn_sched_barrier(0);
        }
    }

    // ---- ||u|| per row: reduce over 4 kd threads (consecutive lanes) ----
    sq += __shfl_xor(sq, 1, 64);
    sq += __shfl_xor(sq, 2, 64);
    if (kd == 0) invnh[row] = 1.0f / (sqrtf(sq) + 1e-8f * nb[bt * 8 + bb]);
    __syncthreads();

    // ---- epilogue: z = acc*invnh + b2; relu; q = sum(Wq*z) ----
    float wqv[8], b2v[8];
#pragma unroll
    for (int nt = 0; nt < 8; nt++) {
        int o = wc * 128 + nt * 16 + l15;
        wqv[nt] = Wq[o]; b2v[nt] = b2[o];
    }
#pragma unroll
    for (int mt = 0; mt < 4; mt++) {
#pragma unroll
        for (int i = 0; i < 4; i++) {
            int R = wr * 64 + mt * 16 + l4 * 4 + i;
            float inv = invnh[R];
            float qp = 0.f;
#pragma unroll
            for (int nt = 0; nt < 8; nt++) {
                float z = fmaf(acc[mt][nt][i], inv, b2v[nt]);
                z = fmaxf(z, 0.f);
                qp = fmaf(z, wqv[nt], qp);
            }
            qp += __shfl_xor(qp, 1, 64);
            qp += __shfl_xor(qp, 2, 64);
            qp += __shfl_xor(qp, 4, 64);
            qp += __shfl_xor(qp, 8, 64);
            if (l15 == 0) qred[R][wc] = qp;
        }
    }
    __syncthreads();
    if (t < 128) {
        float qv = qred[t][0] + qred[t][1] + qred[t][2] + qred[t][3] + bq[0];
        int aa = at * 16 + (t >> 3);
        int bo = bt * 8 + (t & 7);
        out[(size_t)bo * NA + aa] = qv;
    }
}

extern "C" void kernel_launch(void* const* d_in, const int* in_sizes, int n_in,
                              void* d_out, int out_size, void* d_ws, size_t ws_size,
                              hipStream_t stream) {
    const float* states = (const float*)d_in[0];
    const float* W1     = (const float*)d_in[1];
    const float* b1     = (const float*)d_in[2];
    const float* W2     = (const float*)d_in[3];
    const float* b2     = (const float*)d_in[4];
    const float* Wq     = (const float*)d_in[5];
    const float* bq     = (const float*)d_in[6];
    float* out = (float*)d_out;

    char* ws = (char*)d_ws;
    unsigned short* Gt   = (unsigned short*)ws;                              // 8 MB
    unsigned short* W2f  = (unsigned short*)(ws + (8u << 20));               // 1 MB
    unsigned short* caT2 = (unsigned short*)(ws + (9u << 20));               // 128 KB
    float*          nbp  = (float*)(ws + (9u << 20) + (128u << 10));         // 16 KB

    knorm<<<NB, 64, 0, stream>>>(states, nbp);
    kprep<<<2304, 256, 0, stream>>>(W1, W2, W2f, caT2);
    kgemm1<<<256, 256, 0, stream>>>(states, W1, b1, nbp, Gt);
    kmain<<<2048, 512, 0, stream>>>(Gt, caT2, W2f, nbp, b2, Wq, bq, out);
}

// Round 6
// 346.388 us; speedup vs baseline: 1.3094x; 1.0435x over previous
//
#include <hip/hip_runtime.h>
#include <stdint.h>

#define NB 4096
#define NS 512
#define NA 64
#define NH1 1024
#define NH2 512

typedef __attribute__((ext_vector_type(8))) short bf16x8;
typedef __attribute__((ext_vector_type(4))) float f32x4;

__device__ __forceinline__ unsigned short f2bf(float f) {
    union { float f; unsigned u; } v; v.f = f;
    return (unsigned short)((v.u + 0x8000u) >> 16);   // round-half-up bf16
}
__device__ __forceinline__ float bf2f(unsigned short h) {
    union { float f; unsigned u; } v; v.u = ((unsigned)h) << 16;
    return v.f;
}
__device__ __forceinline__ float bflo(unsigned u) {
    union { unsigned u; float f; } v; v.u = u << 16; return v.f;
}
__device__ __forceinline__ float bfhi(unsigned u) {
    union { unsigned u; float f; } v; v.u = u & 0xFFFF0000u; return v.f;
}
// truncating pack of two f32 -> bf16x2 (bias cancels in u/||u||): 1 v_perm
__device__ __forceinline__ unsigned packtrunc(float lo, float hi) {
    union { float f; unsigned u; } a, b; a.f = lo; b.f = hi;
    return __builtin_amdgcn_perm(b.u, a.u, 0x07060302u);
}
__device__ __forceinline__ void split2(float x, unsigned short& h, unsigned short& l) {
    unsigned short hh = f2bf(x);
    h = hh;
    l = f2bf(x - bf2f(hh));
}

// ---------------- P0: nb[b] = sqrt(||s_b||^2 + 1) + 1e-8 ----------------
__global__ void knorm(const float* __restrict__ S, float* __restrict__ nb) {
    int b = blockIdx.x; int l = threadIdx.x; // one wave
    const float* row = S + b * NS;
    float s = 0.f;
    for (int k = l; k < NS; k += 64) { float v = row[k]; s = fmaf(v, v, s); }
    for (int off = 32; off; off >>= 1) s += __shfl_down(s, off, 64);
    if (l == 0) nb[b] = sqrtf(s + 1.0f) + 1e-8f;
}

// ---------------- P1: W2f (frag-packed per-kc tiles, swizzled) + caT2 ----------------
// W2f short idx = ((kc*32 + c)*64 + l)*8 + j :
//   n = c*16 + (l>>2);  g = (l&3) ^ ((n>>1)&3);  value = W2[n][kc*32 + g*8 + j]
// Per-kc tile = 32*64*8 shorts = 32 KB
// caT2[at][kc][a_loc][kk] = W1[(kc*32+kk)*576 + 512 + at*16 + a_loc]
__global__ void kprep(const float* __restrict__ W1, const float* __restrict__ W2,
                      unsigned short* __restrict__ W2f, unsigned short* __restrict__ caT2) {
    int i = blockIdx.x * 256 + threadIdx.x;
    if (i < 524288) {
        int j = i & 7; int l = (i >> 3) & 63; int c = (i >> 9) & 31; int kc = i >> 14;
        int n = c * 16 + (l >> 2);
        int g = (l & 3) ^ ((n >> 1) & 3);
        int k = kc * 32 + g * 8 + j;
        W2f[i] = f2bf(W2[(size_t)n * NH1 + k]);
    } else {
        int j2 = i - 524288;                 // 65536 entries
        int kk = j2 & 31; int a_loc = (j2 >> 5) & 15;
        int kc = (j2 >> 9) & 31; int att = j2 >> 14;
        int o = kc * 32 + kk;
        caT2[j2] = f2bf(W1[(size_t)o * 576 + 512 + att * 16 + a_loc]);
    }
}

// ---------------- P2: Gt'[kc][b][32k] bf16 = s@W1s^T + b1*nb  (split-bf16, 3 GEMMs) ----
__global__ __launch_bounds__(256) void kgemm1(
        const float* __restrict__ Sm, const float* __restrict__ W1,
        const float* __restrict__ b1, const float* __restrict__ nb,
        unsigned short* __restrict__ Gt) {
    const int m0 = (blockIdx.x >> 3) * 128;
    const int n0 = (blockIdx.x & 7) * 128;
    __shared__ unsigned short Ah[128][40], Al[128][40], Bh[128][40], Bl[128][40];
    int t = threadIdx.x;
    int lane = t & 63, wave = t >> 6;
    int wr = wave >> 1, wc = wave & 1;
    int qd = lane >> 4, cl = lane & 15;
    int r = t >> 1, seg = t & 1;
    f32x4 acc[4][4] = {};

    for (int k0 = 0; k0 < 512; k0 += 32) {
        {
            const float4* as4 = (const float4*)(Sm + (size_t)(m0 + r) * NS + k0 + seg * 16);
            const float4* bs4 = (const float4*)(W1 + (size_t)(n0 + r) * 576 + k0 + seg * 16);
            unsigned* ah = (unsigned*)&Ah[r][seg * 16];
            unsigned* al = (unsigned*)&Al[r][seg * 16];
            unsigned* bh = (unsigned*)&Bh[r][seg * 16];
            unsigned* bl = (unsigned*)&Bl[r][seg * 16];
#pragma unroll
            for (int v = 0; v < 4; v++) {
                float4 fa = as4[v];
                unsigned short h0,h1,h2,h3,l0,l1,l2,l3;
                split2(fa.x,h0,l0); split2(fa.y,h1,l1); split2(fa.z,h2,l2); split2(fa.w,h3,l3);
                ah[v*2]   = (unsigned)h0 | ((unsigned)h1 << 16);
                ah[v*2+1] = (unsigned)h2 | ((unsigned)h3 << 16);
                al[v*2]   = (unsigned)l0 | ((unsigned)l1 << 16);
                al[v*2+1] = (unsigned)l2 | ((unsigned)l3 << 16);
                float4 fb = bs4[v];
                split2(fb.x,h0,l0); split2(fb.y,h1,l1); split2(fb.z,h2,l2); split2(fb.w,h3,l3);
                bh[v*2]   = (unsigned)h0 | ((unsigned)h1 << 16);
                bh[v*2+1] = (unsigned)h2 | ((unsigned)h3 << 16);
                bl[v*2]   = (unsigned)l0 | ((unsigned)l1 << 16);
                bl[v*2+1] = (unsigned)l2 | ((unsigned)l3 << 16);
            }
        }
        __syncthreads();
        bf16x8 a_h[4], a_l[4], b_h[4], b_l[4];
#pragma unroll
        for (int mt = 0; mt < 4; mt++) {
            a_h[mt] = *(const bf16x8*)&Ah[wr*64 + mt*16 + cl][qd*8];
            a_l[mt] = *(const bf16x8*)&Al[wr*64 + mt*16 + cl][qd*8];
        }
#pragma unroll
        for (int nt = 0; nt < 4; nt++) {
            b_h[nt] = *(const bf16x8*)&Bh[wc*64 + nt*16 + cl][qd*8];
            b_l[nt] = *(const bf16x8*)&Bl[wc*64 + nt*16 + cl][qd*8];
        }
#pragma unroll
        for (int mt = 0; mt < 4; mt++)
#pragma unroll
            for (int nt = 0; nt < 4; nt++) {
                acc[mt][nt] = __builtin_amdgcn_mfma_f32_16x16x32_bf16(a_h[mt], b_h[nt], acc[mt][nt], 0, 0, 0);
                acc[mt][nt] = __builtin_amdgcn_mfma_f32_16x16x32_bf16(a_h[mt], b_l[nt], acc[mt][nt], 0, 0, 0);
                acc[mt][nt] = __builtin_amdgcn_mfma_f32_16x16x32_bf16(a_l[mt], b_h[nt], acc[mt][nt], 0, 0, 0);
            }
        __syncthreads();
    }
#pragma unroll
    for (int mt = 0; mt < 4; mt++)
#pragma unroll
        for (int i = 0; i < 4; i++) {
            int m = m0 + wr*64 + mt*16 + qd*4 + i;
            float nbv = nb[m];
#pragma unroll
            for (int nt = 0; nt < 4; nt++) {
                int n = n0 + wc*64 + nt*16 + cl;
                float val = fmaf(b1[n], nbv, acc[mt][nt][i]);
                Gt[((size_t)(n >> 5) * NB + m) * 32 + (n & 31)] = f2bf(val);
            }
        }
}

// ---------------- Main: 512 thr, 128 rows (16a x 8b) x 512 cols, K=1024, Kc=32 ----------
// grid 2048 = 512 bt x 4 at. 8 waves: wr = w>>2 (row half), wc = w&3 (col quarter).
// R11: half-granularity register pipeline for the global-B path. R10 issued all
// 8 bfr loads AFTER the 32-MFMA block -> L2 drain (~1150 cyc/CU for 64 KB) ran
// while the matrix pipe idled, then MFMAs ran with nothing in flight (serial
// 1242+1200 ~= 2800 cyc/iter observed). Here bfr is split L[4]/H[4] (same 32
// regs): MFMA on L (16 mfma, ~620 cyc) covers the in-flight H loads; then issue
// L'(kc+1) into L's regs (WAR reuse, dead after the L MFMAs); MFMA on H covers
// L'; issue H'. Every MFMA half hides one load half; load->use distance ~900 cyc.
__global__ __launch_bounds__(512, 2) void kmain(
        const unsigned short* __restrict__ Gt,    // [32][4096][32]
        const unsigned short* __restrict__ caT2,  // [4][32][16][32]
        const unsigned short* __restrict__ W2f,   // per-kc frag-packed tiles (32 KB each)
        const float* __restrict__ nb,
        const float* __restrict__ b2, const float* __restrict__ Wq,
        const float* __restrict__ bq, float* __restrict__ out) {
    int bid = blockIdx.x;
    int at = bid & 3;
    int bt = bid >> 2;

    __shared__ __align__(16) unsigned short As[2][128][40];  // 2 x 10 KB dbuf, pad +8
    __shared__ float invnh[128];
    __shared__ float qred[128][4];

    int t = threadIdx.x;
    int lane = t & 63, w = t >> 6;
    int wr = w >> 2, wc = w & 3;
    int l15 = lane & 15, l4 = lane >> 4;

    // A-gen role: thread owns row (t>>2), k-octet (t&3); 8 elements/iter
    int row = t >> 2, kd = t & 3;
    int ab = row >> 3, bb = row & 7;
    const unsigned short* gG = Gt + ((size_t)(bt * 8 + bb)) * 32 + kd * 8;
    const unsigned short* gC = caT2 + (size_t)at * 16384 + ab * 32 + kd * 8;

    float sq = 0.f;
    f32x4 acc[4][8] = {};
    bf16x8 g_v, c_v;

    auto agen = [&](int s) {
        const unsigned* gd = (const unsigned*)&g_v;
        const unsigned* cd = (const unsigned*)&c_v;
        unsigned ow[4];
#pragma unroll
        for (int p = 0; p < 4; p++) {
            float u0 = fmaxf(bflo(gd[p]) + bflo(cd[p]), 0.f);
            float u1 = fmaxf(bfhi(gd[p]) + bfhi(cd[p]), 0.f);
            sq = fmaf(u0, u0, sq);
            sq = fmaf(u1, u1, sq);
            ow[p] = packtrunc(u0, u1);
        }
        *(bf16x8*)&As[s][row][kd * 8] = *(bf16x8*)ow;
    };

    // B frag source: de-swizzled per-lane global address, iter-invariant offset
    const int boff = (wc * 128 + l15) * 32 + ((l4 ^ ((l15 >> 1) & 3)) << 3);
    const unsigned short* gB = W2f + boff;

    bf16x8 bfrL[4], bfrH[4];

    // prologue: gen(0), bfr(kc0) loads, prefetch g/c(1)
    g_v = *(const bf16x8*)gG;
    c_v = *(const bf16x8*)gC;
    agen(0);
#pragma unroll
    for (int j = 0; j < 4; j++)
        bfrL[j] = *(const bf16x8*)(gB + j * 512);
#pragma unroll
    for (int j = 0; j < 4; j++)
        bfrH[j] = *(const bf16x8*)(gB + (4 + j) * 512);
    gB += 16384;
    gG += (size_t)NB * 32;
    gC += 512;
    g_v = *(const bf16x8*)gG;
    c_v = *(const bf16x8*)gC;
    asm volatile("s_waitcnt lgkmcnt(0)" ::: "memory");   // agen(0) write visible
    __builtin_amdgcn_s_barrier();
    __builtin_amdgcn_sched_barrier(0);

    for (int it = 0; it < 32; ++it) {
        int s = it & 1;

        // ---- A frags from LDS (only LDS consumer left) ----
        bf16x8 af[4];
#pragma unroll
        for (int mt = 0; mt < 4; mt++)
            af[mt] = *(const bf16x8*)&As[s][wr * 64 + mt * 16 + l15][l4 * 8];

        // ---- produce next A tile + prefetch g/c(it+2) ----
        if (it < 31) agen(s ^ 1);
        if (it < 30) {
            gG += (size_t)NB * 32;
            gC += 512;
            g_v = *(const bf16x8*)gG;
            c_v = *(const bf16x8*)gC;
        }

        // ---- MFMA on L half (bfrH(kc) still draining under this) ----
        __builtin_amdgcn_s_setprio(1);
#pragma unroll
        for (int nt = 0; nt < 4; nt++)
#pragma unroll
            for (int mt = 0; mt < 4; mt++)
                acc[mt][nt] = __builtin_amdgcn_mfma_f32_16x16x32_bf16(af[mt], bfrL[nt], acc[mt][nt], 0, 0, 0);
        __builtin_amdgcn_s_setprio(0);

        // ---- issue L'(kc+1) into L regs (WAR reuse; drains under H MFMAs) ----
        if (it < 31) {
#pragma unroll
            for (int j = 0; j < 4; j++)
                bfrL[j] = *(const bf16x8*)(gB + j * 512);
        }

        // ---- MFMA on H half (L' draining under this) ----
        __builtin_amdgcn_s_setprio(1);
#pragma unroll
        for (int nt = 0; nt < 4; nt++)
#pragma unroll
            for (int mt = 0; mt < 4; mt++)
                acc[mt][4 + nt] = __builtin_amdgcn_mfma_f32_16x16x32_bf16(af[mt], bfrH[nt], acc[mt][4 + nt], 0, 0, 0);
        __builtin_amdgcn_s_setprio(0);

        // ---- issue H'(kc+1); As dbuf flip ----
        if (it < 31) {
#pragma unroll
            for (int j = 0; j < 4; j++)
                bfrH[j] = *(const bf16x8*)(gB + (4 + j) * 512);
            gB += 16384;
            asm volatile("s_waitcnt lgkmcnt(0)" ::: "memory");  // agen write + af reads done
            __builtin_amdgcn_s_barrier();
            __builtin_amdgcn_sched_barrier(0);
        }
    }

    // ---- ||u|| per row: reduce over 4 kd threads (consecutive lanes) ----
    sq += __shfl_xor(sq, 1, 64);
    sq += __shfl_xor(sq, 2, 64);
    if (kd == 0) invnh[row] = 1.0f / (sqrtf(sq) + 1e-8f * nb[bt * 8 + bb]);
    __syncthreads();

    // ---- epilogue: z = acc*invnh + b2; relu; q = sum(Wq*z) ----
    float wqv[8], b2v[8];
#pragma unroll
    for (int nt = 0; nt < 8; nt++) {
        int o = wc * 128 + nt * 16 + l15;
        wqv[nt] = Wq[o]; b2v[nt] = b2[o];
    }
#pragma unroll
    for (int mt = 0; mt < 4; mt++) {
#pragma unroll
        for (int i = 0; i < 4; i++) {
            int R = wr * 64 + mt * 16 + l4 * 4 + i;
            float inv = invnh[R];
            float qp = 0.f;
#pragma unroll
            for (int nt = 0; nt < 8; nt++) {
                float z = fmaf(acc[mt][nt][i], inv, b2v[nt]);
                z = fmaxf(z, 0.f);
                qp = fmaf(z, wqv[nt], qp);
            }
            qp += __shfl_xor(qp, 1, 64);
            qp += __shfl_xor(qp, 2, 64);
            qp += __shfl_xor(qp, 4, 64);
            qp += __shfl_xor(qp, 8, 64);
            if (l15 == 0) qred[R][wc] = qp;
        }
    }
    __syncthreads();
    if (t < 128) {
        float qv = qred[t][0] + qred[t][1] + qred[t][2] + qred[t][3] + bq[0];
        int aa = at * 16 + (t >> 3);
        int bo = bt * 8 + (t & 7);
        out[(size_t)bo * NA + aa] = qv;
    }
}

extern "C" void kernel_launch(void* const* d_in, const int* in_sizes, int n_in,
                              void* d_out, int out_size, void* d_ws, size_t ws_size,
                              hipStream_t stream) {
    const float* states = (const float*)d_in[0];
    const float* W1     = (const float*)d_in[1];
    const float* b1     = (const float*)d_in[2];
    const float* W2     = (const float*)d_in[3];
    const float* b2     = (const float*)d_in[4];
    const float* Wq     = (const float*)d_in[5];
    const float* bq     = (const float*)d_in[6];
    float* out = (float*)d_out;

    char* ws = (char*)d_ws;
    unsigned short* Gt   = (unsigned short*)ws;                              // 8 MB
    unsigned short* W2f  = (unsigned short*)(ws + (8u << 20));               // 1 MB
    unsigned short* caT2 = (unsigned short*)(ws + (9u << 20));               // 128 KB
    float*          nbp  = (float*)(ws + (9u << 20) + (128u << 10));         // 16 KB

    knorm<<<NB, 64, 0, stream>>>(states, nbp);
    kprep<<<2304, 256, 0, stream>>>(W1, W2, W2f, caT2);
    kgemm1<<<256, 256, 0, stream>>>(states, W1, b1, nbp, Gt);
    kmain<<<2048, 512, 0, stream>>>(Gt, caT2, W2f, nbp, b2, Wq, bq, out);
}

// Round 7
// 325.276 us; speedup vs baseline: 1.3944x; 1.0649x over previous
//
#include <hip/hip_runtime.h>
#include <stdint.h>

#define NB 4096
#define NS 512
#define NA 64
#define NH1 1024
#define NH2 512

typedef __attribute__((ext_vector_type(8))) short bf16x8;
typedef __attribute__((ext_vector_type(4))) float f32x4;

__device__ __forceinline__ unsigned short f2bf(float f) {
    union { float f; unsigned u; } v; v.f = f;
    return (unsigned short)((v.u + 0x8000u) >> 16);   // round-half-up bf16
}
__device__ __forceinline__ float bf2f(unsigned short h) {
    union { float f; unsigned u; } v; v.u = ((unsigned)h) << 16;
    return v.f;
}
__device__ __forceinline__ float bflo(unsigned u) {
    union { unsigned u; float f; } v; v.u = u << 16; return v.f;
}
__device__ __forceinline__ float bfhi(unsigned u) {
    union { unsigned u; float f; } v; v.u = u & 0xFFFF0000u; return v.f;
}
// truncating pack of two f32 -> bf16x2 (bias cancels in u/||u||): 1 v_perm
__device__ __forceinline__ unsigned packtrunc(float lo, float hi) {
    union { float f; unsigned u; } a, b; a.f = lo; b.f = hi;
    return __builtin_amdgcn_perm(b.u, a.u, 0x07060302u);
}
__device__ __forceinline__ void split2(float x, unsigned short& h, unsigned short& l) {
    unsigned short hh = f2bf(x);
    h = hh;
    l = f2bf(x - bf2f(hh));
}

// ---------------- P0: nb[b] = sqrt(||s_b||^2 + 1) + 1e-8 ----------------
__global__ void knorm(const float* __restrict__ S, float* __restrict__ nb) {
    int b = blockIdx.x; int l = threadIdx.x; // one wave
    const float* row = S + b * NS;
    float s = 0.f;
    for (int k = l; k < NS; k += 64) { float v = row[k]; s = fmaf(v, v, s); }
    for (int off = 32; off; off >>= 1) s += __shfl_down(s, off, 64);
    if (l == 0) nb[b] = sqrtf(s + 1.0f) + 1e-8f;
}

// ---------------- P1: W2f (frag-packed per-kc tiles, swizzled) + caT2 ----------------
// W2f short idx = ((kc*32 + c)*64 + l)*8 + j :
//   n = c*16 + (l>>2);  g = (l&3) ^ ((n>>1)&3);  value = W2[n][kc*32 + g*8 + j]
// Per-kc tile = 32*64*8 shorts = 32 KB
// caT2[at][kc][a_loc][kk] = W1[(kc*32+kk)*576 + 512 + at*16 + a_loc]
__global__ void kprep(const float* __restrict__ W1, const float* __restrict__ W2,
                      unsigned short* __restrict__ W2f, unsigned short* __restrict__ caT2) {
    int i = blockIdx.x * 256 + threadIdx.x;
    if (i < 524288) {
        int j = i & 7; int l = (i >> 3) & 63; int c = (i >> 9) & 31; int kc = i >> 14;
        int n = c * 16 + (l >> 2);
        int g = (l & 3) ^ ((n >> 1) & 3);
        int k = kc * 32 + g * 8 + j;
        W2f[i] = f2bf(W2[(size_t)n * NH1 + k]);
    } else {
        int j2 = i - 524288;                 // 65536 entries
        int kk = j2 & 31; int a_loc = (j2 >> 5) & 15;
        int kc = (j2 >> 9) & 31; int att = j2 >> 14;
        int o = kc * 32 + kk;
        caT2[j2] = f2bf(W1[(size_t)o * 576 + 512 + att * 16 + a_loc]);
    }
}

// ---------------- P2: Gt'[kc][b][32k] bf16 = s@W1s^T + b1*nb  (split-bf16, 3 GEMMs) ----
__global__ __launch_bounds__(256) void kgemm1(
        const float* __restrict__ Sm, const float* __restrict__ W1,
        const float* __restrict__ b1, const float* __restrict__ nb,
        unsigned short* __restrict__ Gt) {
    const int m0 = (blockIdx.x >> 3) * 128;
    const int n0 = (blockIdx.x & 7) * 128;
    __shared__ unsigned short Ah[128][40], Al[128][40], Bh[128][40], Bl[128][40];
    int t = threadIdx.x;
    int lane = t & 63, wave = t >> 6;
    int wr = wave >> 1, wc = wave & 1;
    int qd = lane >> 4, cl = lane & 15;
    int r = t >> 1, seg = t & 1;
    f32x4 acc[4][4] = {};

    for (int k0 = 0; k0 < 512; k0 += 32) {
        {
            const float4* as4 = (const float4*)(Sm + (size_t)(m0 + r) * NS + k0 + seg * 16);
            const float4* bs4 = (const float4*)(W1 + (size_t)(n0 + r) * 576 + k0 + seg * 16);
            unsigned* ah = (unsigned*)&Ah[r][seg * 16];
            unsigned* al = (unsigned*)&Al[r][seg * 16];
            unsigned* bh = (unsigned*)&Bh[r][seg * 16];
            unsigned* bl = (unsigned*)&Bl[r][seg * 16];
#pragma unroll
            for (int v = 0; v < 4; v++) {
                float4 fa = as4[v];
                unsigned short h0,h1,h2,h3,l0,l1,l2,l3;
                split2(fa.x,h0,l0); split2(fa.y,h1,l1); split2(fa.z,h2,l2); split2(fa.w,h3,l3);
                ah[v*2]   = (unsigned)h0 | ((unsigned)h1 << 16);
                ah[v*2+1] = (unsigned)h2 | ((unsigned)h3 << 16);
                al[v*2]   = (unsigned)l0 | ((unsigned)l1 << 16);
                al[v*2+1] = (unsigned)l2 | ((unsigned)l3 << 16);
                float4 fb = bs4[v];
                split2(fb.x,h0,l0); split2(fb.y,h1,l1); split2(fb.z,h2,l2); split2(fb.w,h3,l3);
                bh[v*2]   = (unsigned)h0 | ((unsigned)h1 << 16);
                bh[v*2+1] = (unsigned)h2 | ((unsigned)h3 << 16);
                bl[v*2]   = (unsigned)l0 | ((unsigned)l1 << 16);
                bl[v*2+1] = (unsigned)l2 | ((unsigned)l3 << 16);
            }
        }
        __syncthreads();
        bf16x8 a_h[4], a_l[4], b_h[4], b_l[4];
#pragma unroll
        for (int mt = 0; mt < 4; mt++) {
            a_h[mt] = *(const bf16x8*)&Ah[wr*64 + mt*16 + cl][qd*8];
            a_l[mt] = *(const bf16x8*)&Al[wr*64 + mt*16 + cl][qd*8];
        }
#pragma unroll
        for (int nt = 0; nt < 4; nt++) {
            b_h[nt] = *(const bf16x8*)&Bh[wc*64 + nt*16 + cl][qd*8];
            b_l[nt] = *(const bf16x8*)&Bl[wc*64 + nt*16 + cl][qd*8];
        }
#pragma unroll
        for (int mt = 0; mt < 4; mt++)
#pragma unroll
            for (int nt = 0; nt < 4; nt++) {
                acc[mt][nt] = __builtin_amdgcn_mfma_f32_16x16x32_bf16(a_h[mt], b_h[nt], acc[mt][nt], 0, 0, 0);
                acc[mt][nt] = __builtin_amdgcn_mfma_f32_16x16x32_bf16(a_h[mt], b_l[nt], acc[mt][nt], 0, 0, 0);
                acc[mt][nt] = __builtin_amdgcn_mfma_f32_16x16x32_bf16(a_l[mt], b_h[nt], acc[mt][nt], 0, 0, 0);
            }
        __syncthreads();
    }
#pragma unroll
    for (int mt = 0; mt < 4; mt++)
#pragma unroll
        for (int i = 0; i < 4; i++) {
            int m = m0 + wr*64 + mt*16 + qd*4 + i;
            float nbv = nb[m];
#pragma unroll
            for (int nt = 0; nt < 4; nt++) {
                int n = n0 + wc*64 + nt*16 + cl;
                float val = fmaf(b1[n], nbv, acc[mt][nt][i]);
                Gt[((size_t)(n >> 5) * NB + m) * 32 + (n & 31)] = f2bf(val);
            }
        }
}

// ---------------- Main: 256 thr, 64 rows (16a x 4b) x 512 cols, K=1024, Kc=32 ----------
// R12: 4-wave blocks for cross-block SIMD de-phasing. Registers pin occupancy
// at 2 waves/SIMD; with the old 8-wave block those 2 waves were barrier-synced
// siblings -> phase-locked (af-read storm / MFMA burst / load window all
// aligned, matrix pipe idle between). Now block = 64 rows x 512 cols, 4 waves
// (wc 0..3, wr gone), grid 4096: HW round-robins waves over SIMDs so each SIMD
// hosts 1 wave from each of 2 INDEPENDENT blocks -> block B's MFMA burst fills
// the pipe while block A stalls, kc phases drift freely. A-gen stays 1
// unit/thread (no redundancy); q-reduction still sees all 512 cols in-block.
// Same half-granularity bfrL/H register pipeline as R11.
__global__ __launch_bounds__(256, 2) void kmain(
        const unsigned short* __restrict__ Gt,    // [32][4096][32]
        const unsigned short* __restrict__ caT2,  // [4][32][16][32]
        const unsigned short* __restrict__ W2f,   // per-kc frag-packed tiles (32 KB each)
        const float* __restrict__ nb,
        const float* __restrict__ b2, const float* __restrict__ Wq,
        const float* __restrict__ bq, float* __restrict__ out) {
    int bid = blockIdx.x;
    int at = bid & 3;
    int bt = bid >> 2;            // 0..1023, covers b rows bt*4 .. bt*4+3

    __shared__ __align__(16) unsigned short As[2][64][40];  // 2 x 5 KB dbuf, pad +8
    __shared__ float invnh[64];
    __shared__ float qred[64][4];

    int t = threadIdx.x;          // 0..255
    int lane = t & 63, wc = t >> 6;   // wc = wave = col quarter
    int l15 = lane & 15, l4 = lane >> 4;

    // A-gen role: thread owns row (t>>2), k-octet (t&3); 8 elements/iter
    int row = t >> 2, kd = t & 3;     // row 0..63
    int ab = row >> 2, bb = row & 3;  // 16 a x 4 b
    const unsigned short* gG = Gt + ((size_t)(bt * 4 + bb)) * 32 + kd * 8;
    const unsigned short* gC = caT2 + (size_t)at * 16384 + ab * 32 + kd * 8;

    float sq = 0.f;
    f32x4 acc[4][8] = {};
    bf16x8 g_v, c_v;

    auto agen = [&](int s) {
        const unsigned* gd = (const unsigned*)&g_v;
        const unsigned* cd = (const unsigned*)&c_v;
        unsigned ow[4];
#pragma unroll
        for (int p = 0; p < 4; p++) {
            float u0 = fmaxf(bflo(gd[p]) + bflo(cd[p]), 0.f);
            float u1 = fmaxf(bfhi(gd[p]) + bfhi(cd[p]), 0.f);
            sq = fmaf(u0, u0, sq);
            sq = fmaf(u1, u1, sq);
            ow[p] = packtrunc(u0, u1);
        }
        *(bf16x8*)&As[s][row][kd * 8] = *(bf16x8*)ow;
    };

    // B frag source: de-swizzled per-lane global address, iter-invariant offset
    const int boff = (wc * 128 + l15) * 32 + ((l4 ^ ((l15 >> 1) & 3)) << 3);
    const unsigned short* gB = W2f + boff;

    bf16x8 bfrL[4], bfrH[4];

    // prologue: gen(0), bfr(kc0) loads, prefetch g/c(1)
    g_v = *(const bf16x8*)gG;
    c_v = *(const bf16x8*)gC;
    agen(0);
#pragma unroll
    for (int j = 0; j < 4; j++)
        bfrL[j] = *(const bf16x8*)(gB + j * 512);
#pragma unroll
    for (int j = 0; j < 4; j++)
        bfrH[j] = *(const bf16x8*)(gB + (4 + j) * 512);
    gB += 16384;
    gG += (size_t)NB * 32;
    gC += 512;
    g_v = *(const bf16x8*)gG;
    c_v = *(const bf16x8*)gC;
    asm volatile("s_waitcnt lgkmcnt(0)" ::: "memory");   // agen(0) write visible
    __builtin_amdgcn_s_barrier();
    __builtin_amdgcn_sched_barrier(0);

    for (int it = 0; it < 32; ++it) {
        int s = it & 1;

        // ---- A frags from LDS (only LDS consumer left) ----
        bf16x8 af[4];
#pragma unroll
        for (int mt = 0; mt < 4; mt++)
            af[mt] = *(const bf16x8*)&As[s][mt * 16 + l15][l4 * 8];

        // ---- produce next A tile + prefetch g/c(it+2) ----
        if (it < 31) agen(s ^ 1);
        if (it < 30) {
            gG += (size_t)NB * 32;
            gC += 512;
            g_v = *(const bf16x8*)gG;
            c_v = *(const bf16x8*)gC;
        }

        // ---- MFMA on L half (bfrH(kc) still draining under this) ----
        __builtin_amdgcn_s_setprio(1);
#pragma unroll
        for (int nt = 0; nt < 4; nt++)
#pragma unroll
            for (int mt = 0; mt < 4; mt++)
                acc[mt][nt] = __builtin_amdgcn_mfma_f32_16x16x32_bf16(af[mt], bfrL[nt], acc[mt][nt], 0, 0, 0);
        __builtin_amdgcn_s_setprio(0);

        // ---- issue L'(kc+1) into L regs (WAR reuse; drains under H MFMAs) ----
        if (it < 31) {
#pragma unroll
            for (int j = 0; j < 4; j++)
                bfrL[j] = *(const bf16x8*)(gB + j * 512);
        }

        // ---- MFMA on H half (L' draining under this) ----
        __builtin_amdgcn_s_setprio(1);
#pragma unroll
        for (int nt = 0; nt < 4; nt++)
#pragma unroll
            for (int mt = 0; mt < 4; mt++)
                acc[mt][4 + nt] = __builtin_amdgcn_mfma_f32_16x16x32_bf16(af[mt], bfrH[nt], acc[mt][4 + nt], 0, 0, 0);
        __builtin_amdgcn_s_setprio(0);

        // ---- issue H'(kc+1); As dbuf flip ----
        if (it < 31) {
#pragma unroll
            for (int j = 0; j < 4; j++)
                bfrH[j] = *(const bf16x8*)(gB + (4 + j) * 512);
            gB += 16384;
            asm volatile("s_waitcnt lgkmcnt(0)" ::: "memory");  // agen write + af reads done
            __builtin_amdgcn_s_barrier();
            __builtin_amdgcn_sched_barrier(0);
        }
    }

    // ---- ||u|| per row: reduce over 4 kd threads (consecutive lanes) ----
    sq += __shfl_xor(sq, 1, 64);
    sq += __shfl_xor(sq, 2, 64);
    if (kd == 0) invnh[row] = 1.0f / (sqrtf(sq) + 1e-8f * nb[bt * 4 + bb]);
    __syncthreads();

    // ---- epilogue: z = acc*invnh + b2; relu; q = sum(Wq*z) ----
    float wqv[8], b2v[8];
#pragma unroll
    for (int nt = 0; nt < 8; nt++) {
        int o = wc * 128 + nt * 16 + l15;
        wqv[nt] = Wq[o]; b2v[nt] = b2[o];
    }
#pragma unroll
    for (int mt = 0; mt < 4; mt++) {
#pragma unroll
        for (int i = 0; i < 4; i++) {
            int R = mt * 16 + l4 * 4 + i;
            float inv = invnh[R];
            float qp = 0.f;
#pragma unroll
            for (int nt = 0; nt < 8; nt++) {
                float z = fmaf(acc[mt][nt][i], inv, b2v[nt]);
                z = fmaxf(z, 0.f);
                qp = fmaf(z, wqv[nt], qp);
            }
            qp += __shfl_xor(qp, 1, 64);
            qp += __shfl_xor(qp, 2, 64);
            qp += __shfl_xor(qp, 4, 64);
            qp += __shfl_xor(qp, 8, 64);
            if (l15 == 0) qred[R][wc] = qp;
        }
    }
    __syncthreads();
    if (t < 64) {
        float qv = qred[t][0] + qred[t][1] + qred[t][2] + qred[t][3] + bq[0];
        int aa = at * 16 + (t >> 2);
        int bo = bt * 4 + (t & 3);
        out[(size_t)bo * NA + aa] = qv;
    }
}

extern "C" void kernel_launch(void* const* d_in, const int* in_sizes, int n_in,
                              void* d_out, int out_size, void* d_ws, size_t ws_size,
                              hipStream_t stream) {
    const float* states = (const float*)d_in[0];
    const float* W1     = (const float*)d_in[1];
    const float* b1     = (const float*)d_in[2];
    const float* W2     = (const float*)d_in[3];
    const float* b2     = (const float*)d_in[4];
    const float* Wq     = (const float*)d_in[5];
    const float* bq     = (const float*)d_in[6];
    float* out = (float*)d_out;

    char* ws = (char*)d_ws;
    unsigned short* Gt   = (unsigned short*)ws;                              // 8 MB
    unsigned short* W2f  = (unsigned short*)(ws + (8u << 20));               // 1 MB
    unsigned short* caT2 = (unsigned short*)(ws + (9u << 20));               // 128 KB
    float*          nbp  = (float*)(ws + (9u << 20) + (128u << 10));         // 16 KB

    knorm<<<NB, 64, 0, stream>>>(states, nbp);
    kprep<<<2304, 256, 0, stream>>>(W1, W2, W2f, caT2);
    kgemm1<<<256, 256, 0, stream>>>(states, W1, b1, nbp, Gt);
    kmain<<<4096, 256, 0, stream>>>(Gt, caT2, W2f, nbp, b2, Wq, bq, out);
}